// Round 1
// baseline (760.402 us; speedup 1.0000x reference)
//
#include <hip/hip_runtime.h>

// SparseLinear: out[32,65536] = x[32,1024] @ (w * mask)[1024,65536] + b
// Memory-bound: must stream w (256 MB) + mask (256 MB) exactly once.
// Floor = 520 MB / 6.3 TB/s ~= 82.5 us.
//
// Layout: 1 thread per output column j, 32 batch accumulators in VGPRs.
// Per k: 2 coalesced dword loads (w[k][j], mask[k][j]) -> wm = w*m,
// then 32 FMAs with wave-uniform x[i][k] broadcast from LDS (x^T tiles).

#define IN_DIM 1024
#define OUT_DIM 65536
#define BATCH 32
#define KT 256      // k-tile staged in LDS: 256*32*4 = 32 KB
#define BLOCK 256

__global__ __launch_bounds__(BLOCK) void sparse_linear_kernel(
    const float* __restrict__ x, const float* __restrict__ mask,
    const float* __restrict__ w, const float* __restrict__ b,
    float* __restrict__ out) {
  // xT[kl*32 + i] = x[i][k0+kl]; float4 reads at kl*128 B are 16B-aligned.
  __shared__ float xT[KT * BATCH];
  const int tid = threadIdx.x;
  const int j = blockIdx.x * BLOCK + tid;

  float acc[BATCH];
#pragma unroll
  for (int i = 0; i < BATCH; ++i) acc[i] = 0.0f;

  for (int k0 = 0; k0 < IN_DIM; k0 += KT) {
    __syncthreads();
    // Stage x^T tile: consecutive lanes read consecutive kl -> coalesced
    // global reads (x is tiny / L2-resident). LDS write conflicts here are
    // negligible (staging is <2% of tile work; padding would break the
    // 16B-aligned broadcast float4 reads below).
#pragma unroll
    for (int idx = tid; idx < KT * BATCH; idx += BLOCK) {
      int kl = idx & (KT - 1);
      int i = idx >> 8;  // KT == 256
      xT[kl * BATCH + i] = x[i * IN_DIM + k0 + kl];
    }
    __syncthreads();

#pragma unroll 4
    for (int kl = 0; kl < KT; ++kl) {
      size_t row = (size_t)(k0 + kl) * OUT_DIM + (size_t)j;
      float wm = w[row] * mask[row];
      const float4* xp = (const float4*)&xT[kl * BATCH];
#pragma unroll
      for (int i4 = 0; i4 < BATCH / 4; ++i4) {
        float4 xv = xp[i4];  // uniform address -> LDS broadcast, no conflict
        acc[i4 * 4 + 0] = fmaf(xv.x, wm, acc[i4 * 4 + 0]);
        acc[i4 * 4 + 1] = fmaf(xv.y, wm, acc[i4 * 4 + 1]);
        acc[i4 * 4 + 2] = fmaf(xv.z, wm, acc[i4 * 4 + 2]);
        acc[i4 * 4 + 3] = fmaf(xv.w, wm, acc[i4 * 4 + 3]);
      }
    }
  }

  const float bv = b[j];
#pragma unroll
  for (int i = 0; i < BATCH; ++i) {
    out[(size_t)i * OUT_DIM + (size_t)j] = acc[i] + bv;  // coalesced per i
  }
}

extern "C" void kernel_launch(void* const* d_in, const int* in_sizes, int n_in,
                              void* d_out, int out_size, void* d_ws, size_t ws_size,
                              hipStream_t stream) {
  const float* x = (const float*)d_in[0];
  const float* mask = (const float*)d_in[1];
  const float* w = (const float*)d_in[2];
  const float* b = (const float*)d_in[3];
  float* out = (float*)d_out;
  dim3 grid(OUT_DIM / BLOCK);
  dim3 block(BLOCK);
  hipLaunchKernelGGL(sparse_linear_kernel, grid, block, 0, stream,
                     x, mask, w, b, out);
}

// Round 2
// 506.577 us; speedup vs baseline: 1.5011x; 1.5011x over previous
//
#include <hip/hip_runtime.h>

// SparseLinear: out[32,65536] = x[32,1024] @ (w * mask)[1024,65536] + b, fp32.
// Memory-bound floor: stream w+mask once = 512 MB -> ~82 us @ 6.3 TB/s.
//
// R1 post-mortem: 1 block/CU (11.5% occupancy) + per-kl load/use interleave
// -> latency-bound at 8% HBM. Fix: KSPLIT=4 over gridDim.y (16 waves/CU) +
// explicit depth-1 software pipeline with U=8 load groups (16 loads in
// flight per wave), barrier-free main loop.

#define IN_DIM 1024
#define OUT_DIM 65536
#define BATCH 32
#define KSPLIT 4
#define KCHUNK (IN_DIM / KSPLIT)   // 256
#define BLOCK 256
#define U 8
#define NG (KCHUNK / U)            // 32 groups per block

template <bool ATOMIC>
__global__ __launch_bounds__(BLOCK, 4) void sl_partial(
    const float* __restrict__ x, const float* __restrict__ mask,
    const float* __restrict__ w, float* __restrict__ dst) {
  __shared__ float xT[KCHUNK * BATCH];  // 32 KB: xT[kl*32+i] = x[i][k0+kl]
  const int tid = threadIdx.x;
  const int j = blockIdx.x * BLOCK + tid;
  const int kc = blockIdx.y;
  const int k0 = kc * KCHUNK;

  // One-time stage of this block's x chunk (coalesced global reads; the
  // 64-way LDS write conflict here is one-time, ~2K cyc/block, <2%).
#pragma unroll
  for (int it = 0; it < (KCHUNK * BATCH) / BLOCK; ++it) {
    int idx = it * BLOCK + tid;
    int kl = idx & (KCHUNK - 1);
    int i = idx >> 8;  // KCHUNK == 256
    xT[kl * BATCH + i] = x[i * IN_DIM + k0 + kl];
  }
  __syncthreads();  // only barrier in the kernel

  float acc[BATCH];
#pragma unroll
  for (int i = 0; i < BATCH; ++i) acc[i] = 0.0f;

  const float* wp = w + (size_t)k0 * OUT_DIM + j;
  const float* mp = mask + (size_t)k0 * OUT_DIM + j;

  float wA[U], mA[U], wB[U], mB[U];

  auto loadg = [&](int g, float* wv, float* mv) {
#pragma unroll
    for (int u = 0; u < U; ++u) {
      size_t off = (size_t)(g * U + u) * OUT_DIM;
      wv[u] = __builtin_nontemporal_load(wp + off);  // streaming, no reuse
      mv[u] = __builtin_nontemporal_load(mp + off);
    }
  };
  auto computeg = [&](int g, const float* wv, const float* mv) {
#pragma unroll
    for (int u = 0; u < U; ++u) {
      float wm = wv[u] * mv[u];
      const float4* xp = (const float4*)&xT[(g * U + u) * BATCH];
#pragma unroll
      for (int i4 = 0; i4 < BATCH / 4; ++i4) {
        float4 q = xp[i4];  // wave-uniform address -> LDS broadcast
        acc[i4 * 4 + 0] = fmaf(q.x, wm, acc[i4 * 4 + 0]);
        acc[i4 * 4 + 1] = fmaf(q.y, wm, acc[i4 * 4 + 1]);
        acc[i4 * 4 + 2] = fmaf(q.z, wm, acc[i4 * 4 + 2]);
        acc[i4 * 4 + 3] = fmaf(q.w, wm, acc[i4 * 4 + 3]);
      }
    }
  };

  // Depth-1 software pipeline: loads for phase g+1 are issued before the
  // compute of phase g completes -> 16 dword loads (4 KB/wave) in flight.
  loadg(0, wA, mA);
#pragma unroll 1
  for (int g = 0; g < NG; g += 2) {
    loadg(g + 1, wB, mB);  // g+1 <= NG-1 always (NG even)
    computeg(g, wA, mA);
    if (g + 2 < NG) loadg(g + 2, wA, mA);
    computeg(g + 1, wB, mB);
  }

  if (ATOMIC) {
#pragma unroll
    for (int i = 0; i < BATCH; ++i)
      atomicAdd(dst + (size_t)i * OUT_DIM + j, acc[i]);
  } else {
#pragma unroll
    for (int i = 0; i < BATCH; ++i)
      __builtin_nontemporal_store(
          acc[i], dst + (size_t)(kc * BATCH + i) * OUT_DIM + j);
  }
}

// out[i][j] = b[j] + sum_kc partial[kc][i][j]
__global__ __launch_bounds__(BLOCK) void sl_reduce(
    const float* __restrict__ ws, const float* __restrict__ b,
    float* __restrict__ out) {
  const int j4 = blockIdx.x * BLOCK + threadIdx.x;  // float4 column index
  const int i = blockIdx.y;
  const float4 bv = ((const float4*)b)[j4];
  float4 s = bv;
#pragma unroll
  for (int kc = 0; kc < KSPLIT; ++kc) {
    float4 p = ((const float4*)ws)[(size_t)(kc * BATCH + i) * (OUT_DIM / 4) + j4];
    s.x += p.x;
    s.y += p.y;
    s.z += p.z;
    s.w += p.w;
  }
  ((float4*)out)[(size_t)i * (OUT_DIM / 4) + j4] = s;
}

// Atomic fallback init: out[i][j] = b[j]
__global__ __launch_bounds__(BLOCK) void sl_init(
    const float* __restrict__ b, float* __restrict__ out) {
  const int j4 = blockIdx.x * BLOCK + threadIdx.x;
  const float4 bv = ((const float4*)b)[j4];
#pragma unroll
  for (int i = 0; i < BATCH; ++i)
    ((float4*)out)[(size_t)i * (OUT_DIM / 4) + j4] = bv;
}

extern "C" void kernel_launch(void* const* d_in, const int* in_sizes, int n_in,
                              void* d_out, int out_size, void* d_ws, size_t ws_size,
                              hipStream_t stream) {
  const float* x = (const float*)d_in[0];
  const float* mask = (const float*)d_in[1];
  const float* w = (const float*)d_in[2];
  const float* b = (const float*)d_in[3];
  float* out = (float*)d_out;

  const size_t need = (size_t)KSPLIT * BATCH * OUT_DIM * sizeof(float);  // 32 MB
  if (ws_size >= need) {
    hipLaunchKernelGGL((sl_partial<false>), dim3(OUT_DIM / BLOCK, KSPLIT),
                       dim3(BLOCK), 0, stream, x, mask, w, (float*)d_ws);
    hipLaunchKernelGGL(sl_reduce, dim3(OUT_DIM / 4 / BLOCK, BATCH), dim3(BLOCK),
                       0, stream, (const float*)d_ws, b, out);
  } else {
    hipLaunchKernelGGL(sl_init, dim3(OUT_DIM / 4 / BLOCK), dim3(BLOCK), 0,
                       stream, b, out);
    hipLaunchKernelGGL((sl_partial<true>), dim3(OUT_DIM / BLOCK, KSPLIT),
                       dim3(BLOCK), 0, stream, x, mask, w, out);
  }
}